// Round 3
// baseline (2516.381 us; speedup 1.0000x reference)
//
#include <hip/hip_runtime.h>
#include <math.h>

// Problem constants (B, T, D_IN, D_OUT) = (64, 1024, 512, 512)
#define BATCH   64
#define TSTEPS  1024
#define DIN     512
#define DH      512
#define MDIM    (BATCH * TSTEPS)

// ---- K2 residency split (words = packed fp16 row-pairs per column) ----
#define WREGW   180     // words 0..179   (rows 0..359)   in VGPRs
#define WLDSW   76      // words 180..255 (rows 360..511) in LDS
#define WSTRIDE 76      // words per column in LDS (12j mod 32 start-banks: even 8-round b128)
#define K2_LDS_WORDS (512 * WSTRIDE + 2 * 256)
#define K2_LDS_BYTES (K2_LDS_WORDS * 4)   // 157696 <= 163840

typedef _Float16 h2_t  __attribute__((ext_vector_type(2)));
typedef _Float16 f16x8 __attribute__((ext_vector_type(8)));
typedef float    f32x4 __attribute__((ext_vector_type(4)));

__device__ inline unsigned short f2h_bits(float x) {
    _Float16 h = (_Float16)x;
    return __builtin_bit_cast(unsigned short, h);
}
__device__ inline unsigned int pack2h(float lo, float hi) {
    return (unsigned int)f2h_bits(lo) | ((unsigned int)f2h_bits(hi) << 16);
}
__device__ inline float dot2h(unsigned int ha, unsigned int wb, float acc) {
#if __has_builtin(__builtin_amdgcn_fdot2)
    return __builtin_amdgcn_fdot2(__builtin_bit_cast(h2_t, ha),
                                  __builtin_bit_cast(h2_t, wb), acc, false);
#else
    float hl = (float)__builtin_bit_cast(h2_t, ha).x;
    float hh = (float)__builtin_bit_cast(h2_t, ha).y;
    float wl = (float)__builtin_bit_cast(h2_t, wb).x;
    float wh = (float)__builtin_bit_cast(h2_t, wb).y;
    return fmaf(hh, wh, fmaf(hl, wl, acc));
#endif
}
__device__ inline unsigned int rl(unsigned int v, int lane) {
    return (unsigned int)__builtin_amdgcn_readlane((int)v, lane);
}
// fast tanh: 1 - 2/(exp2(2x*log2e)+1); monotone, saturates correctly, ~1e-6 rel
__device__ inline float ftanh(float x) {
    float e = __builtin_amdgcn_exp2f(x * 2.88539008177792681472f);
    return 1.0f - 2.0f * __builtin_amdgcn_rcpf(e + 1.0f);
}

// ---------------------------------------------------------------------------
// K1a: convert x (fp32) -> Xh (fp16), vectorized 8 elems/thread/iter
// ---------------------------------------------------------------------------
__global__ __launch_bounds__(256) void convert_x(const float* __restrict__ x,
                                                 _Float16* __restrict__ xh,
                                                 int nvec) {
    int i = blockIdx.x * blockDim.x + threadIdx.x;
    int stride = gridDim.x * blockDim.x;
    for (; i < nvec; i += stride) {
        const float4* p = (const float4*)x + 2 * (size_t)i;
        float4 a = p[0], b = p[1];
        f16x8 o = { (_Float16)a.x, (_Float16)a.y, (_Float16)a.z, (_Float16)a.w,
                    (_Float16)b.x, (_Float16)b.y, (_Float16)b.z, (_Float16)b.w };
        ((f16x8*)xh)[i] = o;
    }
}

// ---------------------------------------------------------------------------
// K1b: Wt[n][k] = (fp16) W[k][n]   (512x512, LDS tile transpose)
// ---------------------------------------------------------------------------
__global__ __launch_bounds__(256) void transpose_w(const float* __restrict__ W,
                                                   _Float16* __restrict__ Wt) {
    __shared__ float tile[64][65];
    const int t  = threadIdx.x;
    const int c  = t & 63;
    const int r0 = t >> 6;             // 0..3
    const int bn = blockIdx.x & 7;     // 8x8 tiles of 64
    const int bk = blockIdx.x >> 3;
    const int k0 = bk * 64, n0 = bn * 64;
    #pragma unroll
    for (int i = 0; i < 16; ++i)
        tile[r0 + 4 * i][c] = W[(size_t)(k0 + r0 + 4 * i) * DH + n0 + c];
    __syncthreads();
    #pragma unroll
    for (int i = 0; i < 16; ++i)
        Wt[(size_t)(n0 + r0 + 4 * i) * DIN + k0 + c] = (_Float16)tile[c][r0 + 4 * i];
}

// ---------------------------------------------------------------------------
// K1c: XW = Xh @ Wt^T + bias  via mfma_f32_16x16x32_f16
// 128x128 tile, BK=32, 256 threads (4 waves, each 64x64), global_load_lds x16.
// A-frag: lane holds A[m=lane&15][k=(lane>>4)*8+j]; B-frag same form from Wt[n][k].
// C/D:    lane holds C[row=(lane>>4)*4+r][col=lane&15]   (m89-verified)
// ---------------------------------------------------------------------------
__global__ __launch_bounds__(256) void gemm_xw_mfma(const _Float16* __restrict__ Xh,
                                                    const _Float16* __restrict__ Wt,
                                                    const float* __restrict__ bias,
                                                    float* __restrict__ XW) {
    __shared__ __align__(16) _Float16 Ah[128][32];   // 8 KB
    __shared__ __align__(16) _Float16 Bh[128][32];   // 8 KB

    const int tid  = threadIdx.x;
    const int wv   = tid >> 6;
    const int lane = tid & 63;
    const int bn   = blockIdx.x & 3;     // 512/128
    const int bm   = blockIdx.x >> 2;    // 512 m-tiles
    const int m0   = bm * 128;
    const int n0   = bn * 128;

    const int mbase = (wv >> 1) * 64;    // wave quadrant within 128x128
    const int nbase = (wv & 1) * 64;
    const int fr    = lane & 15;         // frag row/col index
    const int fq    = lane >> 4;         // quad

    f32x4 acc[4][4];
    #pragma unroll
    for (int i = 0; i < 4; ++i)
        #pragma unroll
        for (int j = 0; j < 4; ++j)
            acc[i][j] = (f32x4){0.f, 0.f, 0.f, 0.f};

    for (int kc = 0; kc < DIN / 32; ++kc) {
        const int k0 = kc * 32;
#if __has_builtin(__builtin_amdgcn_global_load_lds)
        #pragma unroll
        for (int q = 0; q < 2; ++q) {
            const int rb = wv * 2 + q;           // row-block of 16
            const int gr = (rb * 16) + (lane >> 2);
            const int gc = (lane & 3) * 8;
            const _Float16* ga = Xh + (size_t)(m0 + gr) * DIN + k0 + gc;
            const _Float16* gb = Wt + (size_t)(n0 + gr) * DIN + k0 + gc;
            __builtin_amdgcn_global_load_lds(
                (const __attribute__((address_space(1))) void*)ga,
                (__attribute__((address_space(3))) void*)&Ah[rb * 16][0], 16, 0, 0);
            __builtin_amdgcn_global_load_lds(
                (const __attribute__((address_space(1))) void*)gb,
                (__attribute__((address_space(3))) void*)&Bh[rb * 16][0], 16, 0, 0);
        }
#else
        #pragma unroll
        for (int q = 0; q < 2; ++q) {
            const int h0 = (q * 256 + tid) * 8;          // half-index in [0,4096)
            const int row = h0 >> 5, col = h0 & 31;
            *((uint4*)Ah + (q * 256 + tid)) =
                *(const uint4*)(Xh + (size_t)(m0 + row) * DIN + k0 + col);
            *((uint4*)Bh + (q * 256 + tid)) =
                *(const uint4*)(Wt + (size_t)(n0 + row) * DIN + k0 + col);
        }
#endif
        __syncthreads();

        f16x8 af[4], bf[4];
        #pragma unroll
        for (int mt = 0; mt < 4; ++mt)
            af[mt] = *(const f16x8*)&Ah[mbase + mt * 16 + fr][fq * 8];
        #pragma unroll
        for (int nt = 0; nt < 4; ++nt)
            bf[nt] = *(const f16x8*)&Bh[nbase + nt * 16 + fr][fq * 8];
        #pragma unroll
        for (int mt = 0; mt < 4; ++mt)
            #pragma unroll
            for (int nt = 0; nt < 4; ++nt)
                acc[mt][nt] = __builtin_amdgcn_mfma_f32_16x16x32_f16(
                    af[mt], bf[nt], acc[mt][nt], 0, 0, 0);
        __syncthreads();
    }

    // epilogue: bias add + store
    #pragma unroll
    for (int nt = 0; nt < 4; ++nt) {
        const int col = n0 + nbase + nt * 16 + fr;
        const float bvl = bias[col];
        #pragma unroll
        for (int mt = 0; mt < 4; ++mt) {
            #pragma unroll
            for (int r = 0; r < 4; ++r) {
                const int row = m0 + mbase + mt * 16 + fq * 4 + r;
                XW[(size_t)row * DH + col] = acc[mt][nt][r] + bvl;
            }
        }
    }
}

// ---------------------------------------------------------------------------
// K1 fallback (fp32 VALU GEMM) if workspace too small for fp16 buffers
// ---------------------------------------------------------------------------
__global__ __launch_bounds__(256) void gemm_xw(const float* __restrict__ X,
                                               const float* __restrict__ W,
                                               const float* __restrict__ bias,
                                               float* __restrict__ XW) {
    __shared__ float As[16][68];
    __shared__ float Bs[16][68];
    const int tid = threadIdx.x;
    const int bx  = blockIdx.x & 7;
    const int by  = blockIdx.x >> 3;
    const int m0  = by * 64, n0 = bx * 64;
    const int ty = tid >> 4, tx = tid & 15;
    const int arow = tid >> 2, akq = (tid & 3) * 4;
    const int brow = tid >> 4, bcq = (tid & 15) * 4;
    float acc[4][4] = {{0.f}};
    for (int k0 = 0; k0 < DIN; k0 += 16) {
        float4 av = *(const float4*)&X[(size_t)(m0 + arow) * DIN + k0 + akq];
        float4 bv = *(const float4*)&W[(size_t)(k0 + brow) * DH + n0 + bcq];
        __syncthreads();
        As[akq + 0][arow] = av.x; As[akq + 1][arow] = av.y;
        As[akq + 2][arow] = av.z; As[akq + 3][arow] = av.w;
        *(float4*)&Bs[brow][bcq] = bv;
        __syncthreads();
        #pragma unroll
        for (int k = 0; k < 16; ++k) {
            float4 a = *(const float4*)&As[k][ty * 4];
            float4 b = *(const float4*)&Bs[k][tx * 4];
            float ar[4] = {a.x, a.y, a.z, a.w};
            float br[4] = {b.x, b.y, b.z, b.w};
            #pragma unroll
            for (int i = 0; i < 4; ++i)
                #pragma unroll
                for (int j = 0; j < 4; ++j)
                    acc[i][j] = fmaf(ar[i], br[j], acc[i][j]);
        }
    }
    float4 bv = *(const float4*)&bias[n0 + tx * 4];
    const float br[4] = {bv.x, bv.y, bv.z, bv.w};
    #pragma unroll
    for (int i = 0; i < 4; ++i) {
        float4 o;
        o.x = acc[i][0] + br[0]; o.y = acc[i][1] + br[1];
        o.z = acc[i][2] + br[2]; o.w = acc[i][3] + br[3];
        *(float4*)&XW[(size_t)(m0 + ty * 4 + i) * DH + n0 + tx * 4] = o;
    }
}

// ---------------------------------------------------------------------------
// K2: sequential scan, readlane-broadcast h (VALU) + resident Wr.
// One wg per batch; thread j owns column j.
//  - h (256 packed fp16 words) read by ONE ds_read_b128 per wave per step,
//    then broadcast lane-by-lane via v_readlane -> SGPR operand of v_dot2.
//  - Wr column j: 180 packed words in VGPRs + 76 words in LDS.
//  - LDS pipe per step: 8 h-reads + 152 w-reads (~1800 cyc) < VALU (~2150 cyc).
// ---------------------------------------------------------------------------
__global__ __launch_bounds__(512, 2) void rnn_scan3(const float* __restrict__ XW,
                                                    const float* __restrict__ Wr,
                                                    float* __restrict__ Hout) {
    extern __shared__ unsigned int lds[];
    unsigned int* wrl  = lds;                     // [512][WSTRIDE]
    unsigned int* hbuf = lds + 512 * WSTRIDE;     // [2][256]

    const int b    = blockIdx.x;
    const int j    = threadIdx.x;                 // column 0..511
    const int lane = j & 63;

    // one-time: Wr column j -> 180 packed words in regs
    unsigned int wreg[WREGW];
    #pragma unroll
    for (int p = 0; p < WREGW; ++p) {
        float lo = Wr[(size_t)(2 * p)     * DH + j];
        float hi = Wr[(size_t)(2 * p + 1) * DH + j];
        wreg[p] = pack2h(lo, hi);
    }
    // one-time: words 180..255 -> LDS [col][word]
    unsigned int* wl_my = wrl + (size_t)j * WSTRIDE;
    #pragma unroll
    for (int p = 0; p < WLDSW; ++p) {
        int r0 = 2 * (WREGW + p);
        float lo = Wr[(size_t)r0       * DH + j];
        float hi = Wr[(size_t)(r0 + 1) * DH + j];
        wl_my[p] = pack2h(lo, hi);
    }
    hbuf[j] = 0u;     // zero both h buffers (512 words total)
    __syncthreads();

    const float* xwb = XW + (size_t)b * TSTEPS * DH + j;
    float xwv = xwb[0];
    float h_f = 0.0f;
    int   cur = 0;

    const unsigned int* wl = wrl + (size_t)j * WSTRIDE;

    for (int t = 0; t < TSTEPS; ++t) {
        // whole wave pulls the full 256-word h block: lane l holds words 4l..4l+3
        uint4 hv = *((const uint4*)(hbuf + cur * 256) + lane);

        const int tn = (t + 1 < TSTEPS) ? (t + 1) : (TSTEPS - 1);
        float xwn = xwb[(size_t)tn * DH];

        float a0 = 0.f, a1 = 0.f, a2 = 0.f, a3 = 0.f;

        // register-w part: words 0..179 (g = source lane, 4 words per lane)
        #pragma unroll
        for (int g = 0; g < WREGW / 4; ++g) {          // 45 groups
            unsigned s0 = rl(hv.x, g), s1 = rl(hv.y, g);
            unsigned s2 = rl(hv.z, g), s3 = rl(hv.w, g);
            a0 = dot2h(s0, wreg[4 * g + 0], a0);
            a1 = dot2h(s1, wreg[4 * g + 1], a1);
            a2 = dot2h(s2, wreg[4 * g + 2], a2);
            a3 = dot2h(s3, wreg[4 * g + 3], a3);
        }
        // LDS-w part: words 180..255
        #pragma unroll
        for (int g = WREGW / 4; g < 64; ++g) {         // 19 groups
            uint4 wv = *(const uint4*)(wl + 4 * (g - WREGW / 4));
            unsigned s0 = rl(hv.x, g), s1 = rl(hv.y, g);
            unsigned s2 = rl(hv.z, g), s3 = rl(hv.w, g);
            a0 = dot2h(s0, wv.x, a0);
            a1 = dot2h(s1, wv.y, a1);
            a2 = dot2h(s2, wv.z, a2);
            a3 = dot2h(s3, wv.w, a3);
        }

        h_f = ftanh(((a0 + a1) + (a2 + a3)) + xwv);

        ((unsigned short*)(hbuf + ((cur ^ 1) * 256)))[j] = f2h_bits(h_f);
        __syncthreads();
        cur ^= 1;
        xwv = xwn;
    }

    Hout[(size_t)b * DH + j] = h_f;
}

// ---------------------------------------------------------------------------
// launch
// ---------------------------------------------------------------------------
extern "C" void kernel_launch(void* const* d_in, const int* in_sizes, int n_in,
                              void* d_out, int out_size, void* d_ws, size_t ws_size,
                              hipStream_t stream) {
    const float* x  = (const float*)d_in[0];
    const float* W  = (const float*)d_in[1];
    const float* Wr = (const float*)d_in[2];
    const float* bv = (const float*)d_in[3];
    float* out = (float*)d_out;

    const size_t XW_BYTES = (size_t)MDIM * DH * sizeof(float);      // 134.2 MB
    const size_t XH_BYTES = (size_t)MDIM * DIN * sizeof(_Float16);  //  67.1 MB
    const size_t WT_BYTES = (size_t)DIN * DH * sizeof(_Float16);    //   0.5 MB
    if (ws_size < XW_BYTES) return;

    float* xw = (float*)d_ws;

    hipFuncSetAttribute((const void*)rnn_scan3,
                        hipFuncAttributeMaxDynamicSharedMemorySize, K2_LDS_BYTES);

    if (ws_size >= XW_BYTES + XH_BYTES + WT_BYTES) {
        _Float16* xh = (_Float16*)((char*)d_ws + XW_BYTES);
        _Float16* wt = (_Float16*)((char*)d_ws + XW_BYTES + XH_BYTES);
        convert_x<<<dim3(2048), dim3(256), 0, stream>>>(x, xh, MDIM * DIN / 8);
        transpose_w<<<dim3(64), dim3(256), 0, stream>>>(W, wt);
        gemm_xw_mfma<<<dim3((MDIM / 128) * (DH / 128)), dim3(256), 0, stream>>>(
            xh, wt, bv, xw);
    } else {
        gemm_xw<<<dim3((MDIM / 64) * (DH / 64)), dim3(256), 0, stream>>>(x, W, bv, xw);
    }

    rnn_scan3<<<dim3(BATCH), dim3(512), K2_LDS_BYTES, stream>>>(xw, Wr, out);
}

// Round 4
// 2078.075 us; speedup vs baseline: 1.2109x; 1.2109x over previous
//
#include <hip/hip_runtime.h>
#include <math.h>

// Problem constants (B, T, D_IN, D_OUT) = (64, 1024, 512, 512)
#define BATCH   64
#define TSTEPS  1024
#define DIN     512
#define DH      512
#define MDIM    (BATCH * TSTEPS)

// ---- K2 (MFMA scan) geometry ----
// 4 workgroups x 512 threads (8 waves). Each wg owns MB=16 batches.
// Wave wv owns output cols [wv*64, wv*64+64) = 4 slices of 16:
//   slices 0..2 -> B-frags resident in VGPRs (3*16 chunks*4 regs = 192 VGPRs)
//   slice  3    -> resident in LDS, read as B-frags each step
// H[16][512] fp16 lives in LDS (single buffer, 2 barriers/step).
#define MB          16
#define HSTRIDE_W   260                 // words per m-row: 512 halves + 8 pad = 260 words (==4 mod 32)
#define H_WORDS     (16 * HSTRIDE_W)    // 4160 words = 16640 B
#define SLICE_WORDS (16 * HSTRIDE_W)    // per 16-col slice: [col][k] padded, 16640 B
#define WRL_WORDS   (8 * SLICE_WORDS)   // 8 LDS slices = 133120 B
#define K2_LDS_WORDS (WRL_WORDS + H_WORDS)
#define K2_LDS_BYTES (K2_LDS_WORDS * 4) // 149760 <= 163840

typedef _Float16 f16x8 __attribute__((ext_vector_type(8)));
typedef float    f32x4 __attribute__((ext_vector_type(4)));

__device__ inline unsigned short f2h_bits(float x) {
    _Float16 h = (_Float16)x;
    return __builtin_bit_cast(unsigned short, h);
}
// fast tanh: 1 - 2/(exp2(2x*log2e)+1); saturates correctly incl. inf
__device__ inline float ftanh(float x) {
    float e = __builtin_amdgcn_exp2f(x * 2.88539008177792681472f);
    return 1.0f - 2.0f * __builtin_amdgcn_rcpf(e + 1.0f);
}

// ---------------------------------------------------------------------------
// K1a: convert x (fp32) -> Xh (fp16)
// ---------------------------------------------------------------------------
__global__ __launch_bounds__(256) void convert_x(const float* __restrict__ x,
                                                 _Float16* __restrict__ xh,
                                                 int nvec) {
    int i = blockIdx.x * blockDim.x + threadIdx.x;
    int stride = gridDim.x * blockDim.x;
    for (; i < nvec; i += stride) {
        const float4* p = (const float4*)x + 2 * (size_t)i;
        float4 a = p[0], b = p[1];
        f16x8 o = { (_Float16)a.x, (_Float16)a.y, (_Float16)a.z, (_Float16)a.w,
                    (_Float16)b.x, (_Float16)b.y, (_Float16)b.z, (_Float16)b.w };
        ((f16x8*)xh)[i] = o;
    }
}

// ---------------------------------------------------------------------------
// K1b: Wt[n][k] = (fp16) W[k][n]
// ---------------------------------------------------------------------------
__global__ __launch_bounds__(256) void transpose_w(const float* __restrict__ W,
                                                   _Float16* __restrict__ Wt) {
    __shared__ float tile[64][65];
    const int t  = threadIdx.x;
    const int c  = t & 63;
    const int r0 = t >> 6;
    const int bn = blockIdx.x & 7;
    const int bk = blockIdx.x >> 3;
    const int k0 = bk * 64, n0 = bn * 64;
    #pragma unroll
    for (int i = 0; i < 16; ++i)
        tile[r0 + 4 * i][c] = W[(size_t)(k0 + r0 + 4 * i) * DH + n0 + c];
    __syncthreads();
    #pragma unroll
    for (int i = 0; i < 16; ++i)
        Wt[(size_t)(n0 + r0 + 4 * i) * DIN + k0 + c] = (_Float16)tile[c][r0 + 4 * i];
}

// ---------------------------------------------------------------------------
// K1c: XW = Xh @ Wt^T + bias via mfma_f32_16x16x32_f16 (validated r2/r3)
// ---------------------------------------------------------------------------
__global__ __launch_bounds__(256) void gemm_xw_mfma(const _Float16* __restrict__ Xh,
                                                    const _Float16* __restrict__ Wt,
                                                    const float* __restrict__ bias,
                                                    float* __restrict__ XW) {
    __shared__ __align__(16) _Float16 Ah[128][32];
    __shared__ __align__(16) _Float16 Bh[128][32];

    const int tid  = threadIdx.x;
    const int wv   = tid >> 6;
    const int lane = tid & 63;
    const int bn   = blockIdx.x & 3;
    const int bm   = blockIdx.x >> 2;
    const int m0   = bm * 128;
    const int n0   = bn * 128;

    const int mbase = (wv >> 1) * 64;
    const int nbase = (wv & 1) * 64;
    const int fr    = lane & 15;
    const int fq    = lane >> 4;

    f32x4 acc[4][4];
    #pragma unroll
    for (int i = 0; i < 4; ++i)
        #pragma unroll
        for (int j = 0; j < 4; ++j)
            acc[i][j] = (f32x4){0.f, 0.f, 0.f, 0.f};

    for (int kc = 0; kc < DIN / 32; ++kc) {
        const int k0 = kc * 32;
#if __has_builtin(__builtin_amdgcn_global_load_lds)
        #pragma unroll
        for (int q = 0; q < 2; ++q) {
            const int rb = wv * 2 + q;
            const int gr = (rb * 16) + (lane >> 2);
            const int gc = (lane & 3) * 8;
            const _Float16* ga = Xh + (size_t)(m0 + gr) * DIN + k0 + gc;
            const _Float16* gb = Wt + (size_t)(n0 + gr) * DIN + k0 + gc;
            __builtin_amdgcn_global_load_lds(
                (const __attribute__((address_space(1))) void*)ga,
                (__attribute__((address_space(3))) void*)&Ah[rb * 16][0], 16, 0, 0);
            __builtin_amdgcn_global_load_lds(
                (const __attribute__((address_space(1))) void*)gb,
                (__attribute__((address_space(3))) void*)&Bh[rb * 16][0], 16, 0, 0);
        }
#else
        #pragma unroll
        for (int q = 0; q < 2; ++q) {
            const int h0 = (q * 256 + tid) * 8;
            const int row = h0 >> 5, col = h0 & 31;
            *((uint4*)Ah + (q * 256 + tid)) =
                *(const uint4*)(Xh + (size_t)(m0 + row) * DIN + k0 + col);
            *((uint4*)Bh + (q * 256 + tid)) =
                *(const uint4*)(Wt + (size_t)(n0 + row) * DIN + k0 + col);
        }
#endif
        __syncthreads();

        f16x8 af[4], bf[4];
        #pragma unroll
        for (int mt = 0; mt < 4; ++mt)
            af[mt] = *(const f16x8*)&Ah[mbase + mt * 16 + fr][fq * 8];
        #pragma unroll
        for (int nt = 0; nt < 4; ++nt)
            bf[nt] = *(const f16x8*)&Bh[nbase + nt * 16 + fr][fq * 8];
        #pragma unroll
        for (int mt = 0; mt < 4; ++mt)
            #pragma unroll
            for (int nt = 0; nt < 4; ++nt)
                acc[mt][nt] = __builtin_amdgcn_mfma_f32_16x16x32_f16(
                    af[mt], bf[nt], acc[mt][nt], 0, 0, 0);
        __syncthreads();
    }

    #pragma unroll
    for (int nt = 0; nt < 4; ++nt) {
        const int col = n0 + nbase + nt * 16 + fr;
        const float bvl = bias[col];
        #pragma unroll
        for (int mt = 0; mt < 4; ++mt) {
            #pragma unroll
            for (int r = 0; r < 4; ++r) {
                const int row = m0 + mbase + mt * 16 + fq * 4 + r;
                XW[(size_t)row * DH + col] = acc[mt][nt][r] + bvl;
            }
        }
    }
}

// ---------------------------------------------------------------------------
// K1 fallback (fp32 VALU GEMM)
// ---------------------------------------------------------------------------
__global__ __launch_bounds__(256) void gemm_xw(const float* __restrict__ X,
                                               const float* __restrict__ W,
                                               const float* __restrict__ bias,
                                               float* __restrict__ XW) {
    __shared__ float As[16][68];
    __shared__ float Bs[16][68];
    const int tid = threadIdx.x;
    const int bx  = blockIdx.x & 7;
    const int by  = blockIdx.x >> 3;
    const int m0  = by * 64, n0 = bx * 64;
    const int ty = tid >> 4, tx = tid & 15;
    const int arow = tid >> 2, akq = (tid & 3) * 4;
    const int brow = tid >> 4, bcq = (tid & 15) * 4;
    float acc[4][4] = {{0.f}};
    for (int k0 = 0; k0 < DIN; k0 += 16) {
        float4 av = *(const float4*)&X[(size_t)(m0 + arow) * DIN + k0 + akq];
        float4 bv = *(const float4*)&W[(size_t)(k0 + brow) * DH + n0 + bcq];
        __syncthreads();
        As[akq + 0][arow] = av.x; As[akq + 1][arow] = av.y;
        As[akq + 2][arow] = av.z; As[akq + 3][arow] = av.w;
        *(float4*)&Bs[brow][bcq] = bv;
        __syncthreads();
        #pragma unroll
        for (int k = 0; k < 16; ++k) {
            float4 a = *(const float4*)&As[k][ty * 4];
            float4 b = *(const float4*)&Bs[k][tx * 4];
            float ar[4] = {a.x, a.y, a.z, a.w};
            float br[4] = {b.x, b.y, b.z, b.w};
            #pragma unroll
            for (int i = 0; i < 4; ++i)
                #pragma unroll
                for (int j = 0; j < 4; ++j)
                    acc[i][j] = fmaf(ar[i], br[j], acc[i][j]);
        }
    }
    float4 bv = *(const float4*)&bias[n0 + tx * 4];
    const float br[4] = {bv.x, bv.y, bv.z, bv.w};
    #pragma unroll
    for (int i = 0; i < 4; ++i) {
        float4 o;
        o.x = acc[i][0] + br[0]; o.y = acc[i][1] + br[1];
        o.z = acc[i][2] + br[2]; o.w = acc[i][3] + br[3];
        *(float4*)&XW[(size_t)(m0 + ty * 4 + i) * DH + n0 + tx * 4] = o;
    }
}

// ---------------------------------------------------------------------------
// K2: batch-stacked MFMA scan. 4 wgs x 512 thr; wg = 16 batches, full 512 cols.
// H_new[16][512] = tanh(H @ Wr + xw_t), H fp16 in LDS, Wr resident (VGPR+LDS).
// Fragment layouts identical to gemm_xw_mfma (validated):
//   A: lane holds H[m=lane&15][k=quad*8+j]       (b128 from LDS, stride 260w)
//   B: lane holds Wr[k=quad*8+j][col=base+lane&15]
//   C: lane holds D[m=quad*4+r][col=base+lane&15]
// ---------------------------------------------------------------------------
__global__ __launch_bounds__(512, 2) void rnn_scan4(const float* __restrict__ XW,
                                                    const float* __restrict__ Wr,
                                                    float* __restrict__ Hout) {
    extern __shared__ unsigned int lds[];
    unsigned int*   wrl = lds;                 // [8 slices][16 cols][260 words]
    unsigned int*   hb  = lds + WRL_WORDS;     // [16 m][260 words]
    unsigned short* hsh = (unsigned short*)hb; // same, half-granular (stride 520)

    const int tid  = threadIdx.x;
    const int wv   = tid >> 6;        // wave 0..7, owns cols [wv*64, wv*64+64)
    const int lane = tid & 63;
    const int fr   = lane & 15;
    const int fq   = lane >> 4;
    const int b0   = blockIdx.x * MB; // batches [b0, b0+16)

    // zero H (h0 = 0), incl. pad words
    for (int i = tid; i < H_WORDS; i += 512) hb[i] = 0u;

    // ---- one-time preload: Wr col-slices -> VGPR B-frags (slices 0..2) ----
    f16x8 breg[3][16];
    #pragma unroll
    for (int s = 0; s < 3; ++s) {
        const int col = wv * 64 + s * 16 + fr;
        #pragma unroll
        for (int c = 0; c < 16; ++c) {
            const int k0 = c * 32 + fq * 8;
            f16x8 v;
            #pragma unroll
            for (int j = 0; j < 8; ++j)
                v[j] = (_Float16)Wr[(size_t)(k0 + j) * DH + col];
            breg[s][c] = v;
        }
    }
    // ---- one-time preload: slice 3 -> LDS, each lane writes its own read addr ----
    {
        const int col = wv * 64 + 48 + fr;
        unsigned int* base = wrl + wv * SLICE_WORDS + fr * HSTRIDE_W + fq * 4;
        #pragma unroll
        for (int c = 0; c < 16; ++c) {
            const int k0 = c * 32 + fq * 8;
            f16x8 v;
            #pragma unroll
            for (int j = 0; j < 8; ++j)
                v[j] = (_Float16)Wr[(size_t)(k0 + j) * DH + col];
            *(uint4*)(base + c * 16) = __builtin_bit_cast(uint4, v);
        }
    }
    __syncthreads();

    const float* xwt = XW + (size_t)(b0 + fq * 4) * TSTEPS * DH + wv * 64 + fr;
    const unsigned int* abase = hb + fr * HSTRIDE_W + fq * 4;
    const unsigned int* bbase = wrl + wv * SLICE_WORDS + fr * HSTRIDE_W + fq * 4;

    #pragma unroll 1
    for (int t = 0; t < TSTEPS; ++t) {
        f32x4 cc[4];
        #pragma unroll
        for (int s = 0; s < 4; ++s) cc[s] = (f32x4){0.f, 0.f, 0.f, 0.f};

        // MFMA over 16 K-chunks; A-frag shared across the wave's 4 col-slices
        #pragma unroll
        for (int c = 0; c < 16; ++c) {
            f16x8 af = __builtin_bit_cast(f16x8, *(const uint4*)(abase + c * 16));
            f16x8 bf = __builtin_bit_cast(f16x8, *(const uint4*)(bbase + c * 16));
            cc[0] = __builtin_amdgcn_mfma_f32_16x16x32_f16(af, breg[0][c], cc[0], 0, 0, 0);
            cc[1] = __builtin_amdgcn_mfma_f32_16x16x32_f16(af, breg[1][c], cc[1], 0, 0, 0);
            cc[2] = __builtin_amdgcn_mfma_f32_16x16x32_f16(af, breg[2][c], cc[2], 0, 0, 0);
            cc[3] = __builtin_amdgcn_mfma_f32_16x16x32_f16(af, bf,         cc[3], 0, 0, 0);
        }

        // xw for this step, loaded in C-frag layout (issued before barrier)
        float xv[4][4];
        #pragma unroll
        for (int s = 0; s < 4; ++s)
            #pragma unroll
            for (int r = 0; r < 4; ++r)
                xv[s][r] = xwt[(size_t)r * TSTEPS * DH + (size_t)t * DH + s * 16];

        __syncthreads();   // all H reads for step t complete

        // epilogue: h = tanh(acc + xw); publish fp16 into H
        #pragma unroll
        for (int s = 0; s < 4; ++s) {
            #pragma unroll
            for (int r = 0; r < 4; ++r) {
                float h = ftanh(cc[s][r] + xv[s][r]);
                hsh[(fq * 4 + r) * (HSTRIDE_W * 2) + wv * 64 + s * 16 + fr] = f2h_bits(h);
            }
        }
        __syncthreads();   // H_{t+1} visible before next step's reads
    }

    // final output from LDS H (coalesced): thread -> (m, 16-col chunk)
    {
        const int m  = tid >> 5;          // 0..15
        const int cb = (tid & 31) * 16;   // 0..496
        #pragma unroll
        for (int g = 0; g < 16; g += 8) {
            f16x8 v = __builtin_bit_cast(f16x8,
                *(const uint4*)(hsh + (size_t)m * (HSTRIDE_W * 2) + cb + g));
            float4 o0 = { (float)v[0], (float)v[1], (float)v[2], (float)v[3] };
            float4 o1 = { (float)v[4], (float)v[5], (float)v[6], (float)v[7] };
            *(float4*)&Hout[(size_t)(b0 + m) * DH + cb + g]     = o0;
            *(float4*)&Hout[(size_t)(b0 + m) * DH + cb + g + 4] = o1;
        }
    }
}

// ---------------------------------------------------------------------------
// launch
// ---------------------------------------------------------------------------
extern "C" void kernel_launch(void* const* d_in, const int* in_sizes, int n_in,
                              void* d_out, int out_size, void* d_ws, size_t ws_size,
                              hipStream_t stream) {
    const float* x  = (const float*)d_in[0];
    const float* W  = (const float*)d_in[1];
    const float* Wr = (const float*)d_in[2];
    const float* bv = (const float*)d_in[3];
    float* out = (float*)d_out;

    const size_t XW_BYTES = (size_t)MDIM * DH * sizeof(float);
    const size_t XH_BYTES = (size_t)MDIM * DIN * sizeof(_Float16);
    const size_t WT_BYTES = (size_t)DIN * DH * sizeof(_Float16);
    if (ws_size < XW_BYTES) return;

    float* xw = (float*)d_ws;

    hipFuncSetAttribute((const void*)rnn_scan4,
                        hipFuncAttributeMaxDynamicSharedMemorySize, K2_LDS_BYTES);

    if (ws_size >= XW_BYTES + XH_BYTES + WT_BYTES) {
        _Float16* xh = (_Float16*)((char*)d_ws + XW_BYTES);
        _Float16* wt = (_Float16*)((char*)d_ws + XW_BYTES + XH_BYTES);
        convert_x<<<dim3(2048), dim3(256), 0, stream>>>(x, xh, MDIM * DIN / 8);
        transpose_w<<<dim3(64), dim3(256), 0, stream>>>(W, wt);
        gemm_xw_mfma<<<dim3((MDIM / 128) * (DH / 128)), dim3(256), 0, stream>>>(
            xh, wt, bv, xw);
    } else {
        gemm_xw<<<dim3((MDIM / 64) * (DH / 64)), dim3(256), 0, stream>>>(x, W, bv, xw);
    }

    rnn_scan4<<<dim3(BATCH / MB), dim3(512), K2_LDS_BYTES, stream>>>(xw, Wr, out);
}